// Round 9
// baseline (175.049 us; speedup 1.0000x reference)
//
#include <hip/hip_runtime.h>
#include <hip/hip_bf16.h>

// Shapes: bz=32, rv_num=10, rv_len=128, in_feat=300, out_feat=128
// N = 320 reviews/side, tokens/side = 40960, M = 1280 tokens/sample.

#define K_FEAT 300
#define H 128
#define NTOK 40960
#define NREV 320
#define TOK_PER_SAMPLE 1280
#define TM 32                       // tokens per fc block
#define FC_BLKS_PER_SIDE 1280       // 40960/32
#define FC_BLKS_PER_SAMPLE 40       // 1280/32
#define NCHUNK 10
#define WFRAG_ELEMS (NCHUNK * 4 * 2 * 64 * 8)   // 40960 f16 = 80 KB

typedef _Float16 f16;
typedef __attribute__((ext_vector_type(8))) _Float16 f16x8;
typedef __attribute__((ext_vector_type(4))) float f32x4;
typedef unsigned short u16;
typedef unsigned int u32;

static __device__ __forceinline__ u16 f2bf(float x) {
    u32 u = __float_as_uint(x);
    return (u16)((u + 0x7fffu + ((u >> 16) & 1u)) >> 16);
}
static __device__ __forceinline__ float bf2f(u16 s) {
    return __uint_as_float(((u32)s) << 16);
}
static __device__ __forceinline__ u16 f2h_bits(float x) {
    f16 h = (f16)x;
    return *(u16*)&h;
}
static __device__ __forceinline__ u32 pk2h(float a, float b) {
    return (u32)f2h_bits(a) | ((u32)f2h_bits(b) << 16);
}

// ---------------- Kernel 0: pack W into f16 MFMA fragments --------------------------------
// Wfrag[c][p][t2][lane][8]; h = (2*p + t2)*16 + (lane&15); k = c*32 + (lane>>4)*8 + j.
// Zero-pad k >= 300. Single f16 term (no hi/lo split).
__global__ void wsplit_kernel(const float* __restrict__ W, u16* __restrict__ Wfrag)
{
    int i = blockIdx.x * 256 + threadIdx.x;
    if (i >= WFRAG_ELEMS) return;
    int j    = i & 7;
    int lane = (i >> 3) & 63;
    int t2   = (i >> 9) & 1;
    int p    = (i >> 10) & 3;
    int c    = i >> 12;
    int nn = lane & 15, quad = lane >> 4;
    int h = (2 * p + t2) * 16 + nn;
    int k = c * 32 + quad * 8 + j;
    float w = (k < K_FEAT) ? W[(size_t)k * H + h] : 0.f;
    Wfrag[i] = f2h_bits(w);
}

// ---------------- Kernel 1: FC + ReLU, f16 MFMA, NO LDS, NO BARRIER ----------------------
// grid.x = 2560; block = 256 (4 waves). Tile 32 tok x 128 feat; wave owns h-pair p=wave.
// Each lane loads its own MFMA A-fragment DIRECTLY from global: lane (nn,quad) needs
// 8 consecutive k of token (m*16+nn) = two float4 loads at compile-time immediate offsets.
// No staging, no LDS round-trip, no lgkmcnt chain, no __syncthreads — pure load->cvt->MFMA
// dataflow the compiler can pipeline arbitrarily deep. A is re-read by the block's 4 waves
// (L1-absorbed); W fragments are L2-hot (shared by all resident blocks).
// k>=300 tail: W is zero-padded there, so A only needs buffer-bounds masking (chunk 9).
__global__ __launch_bounds__(256, 4) void fc_mfma_kernel(
    const float* __restrict__ seq_a, const float* __restrict__ seq_b,
    const u16* __restrict__ Wfrag, const float* __restrict__ bias,
    u16* __restrict__ ta, u16* __restrict__ tb,
    float* __restrict__ psum_a, float* __restrict__ psum_b)
{
    int blk = blockIdx.x;
    const float* seq; u16* outp; float* psum;
    if (blk < FC_BLKS_PER_SIDE) { seq = seq_a; outp = ta; psum = psum_a; }
    else { seq = seq_b; outp = tb; psum = psum_b; blk -= FC_BLKS_PER_SIDE; }

    const int tid = threadIdx.x;
    const int tok0 = blk * TM;
    const int wave = tid >> 6;
    const int lane = tid & 63;
    const int nn = lane & 15;
    const int quad = lane >> 4;

    // Per-lane A row bases: fragment m covers token tok0 + m*16 + nn, k-slice quad*8..+8.
    const float* rowA0 = seq + (size_t)(tok0 + nn) * K_FEAT + quad * 8;
    const float* rowA1 = rowA0 + (size_t)16 * K_FEAT;
    // Per-lane W base: wave's h-pair, this lane's fragment row.
    const u16* wbase = Wfrag + (size_t)wave * 1024 + (size_t)lane * 8;

    f32x4 acc[2][2];                    // [tok-tile m][h-tile t2]
#pragma unroll
    for (int m = 0; m < 2; ++m) {
        acc[m][0] = (f32x4){0.f, 0.f, 0.f, 0.f};
        acc[m][1] = (f32x4){0.f, 0.f, 0.f, 0.f};
    }

#pragma unroll
    for (int c = 0; c < NCHUNK; ++c) {
        f16x8 wh0 = *(const f16x8*)&wbase[(size_t)c * 4096];
        f16x8 wh1 = *(const f16x8*)&wbase[(size_t)c * 4096 + 512];
#pragma unroll
        for (int m = 0; m < 2; ++m) {
            const float* r = (m == 0) ? rowA0 : rowA1;
            float4 af0, af1;
            if (c < 9) {                // compile-time: chunks 0..8 fully in-bounds
                af0 = *(const float4*)(r + c * 32);
                af1 = *(const float4*)(r + c * 32 + 4);
            } else {                    // chunk 9: k = 288 + quad*8 + j; mask k >= 300
                af0 = make_float4(0.f, 0.f, 0.f, 0.f);
                af1 = make_float4(0.f, 0.f, 0.f, 0.f);
                if (quad < 2)  af0 = *(const float4*)(r + c * 32);       // k 288..299
                if (quad == 0) af1 = *(const float4*)(r + c * 32 + 4);   // k 292..299
            }
            uint4 pkt;
            pkt.x = pk2h(af0.x, af0.y);
            pkt.y = pk2h(af0.z, af0.w);
            pkt.z = pk2h(af1.x, af1.y);
            pkt.w = pk2h(af1.z, af1.w);
            f16x8 a = *reinterpret_cast<f16x8*>(&pkt);
            // swapped: D[h][tok]
            acc[m][0] = __builtin_amdgcn_mfma_f32_16x16x32_f16(wh0, a, acc[m][0], 0, 0, 0);
            acc[m][1] = __builtin_amdgcn_mfma_f32_16x16x32_f16(wh1, a, acc[m][1], 0, 0, 0);
        }
    }

    // Epilogue: lane holds h = (2*wave+ht)*16 + quad*4 + r, tok = tok0 + m*16 + nn.
#pragma unroll
    for (int ht = 0; ht < 2; ++ht) {
        const int h0 = (2 * wave + ht) * 16 + quad * 4;
        const float4 bb = *(const float4*)&bias[h0];    // L1-hot global
        float fs[4] = {0.f, 0.f, 0.f, 0.f};
#pragma unroll
        for (int m = 0; m < 2; ++m) {
            int tok = tok0 + m * 16 + nn;
            float v0 = fmaxf(acc[m][ht][0] + bb.x, 0.f);
            float v1 = fmaxf(acc[m][ht][1] + bb.y, 0.f);
            float v2 = fmaxf(acc[m][ht][2] + bb.z, 0.f);
            float v3 = fmaxf(acc[m][ht][3] + bb.w, 0.f);
            fs[0] += v0; fs[1] += v1; fs[2] += v2; fs[3] += v3;
            uint2 pk;
            pk.x = (u32)f2bf(v0) | ((u32)f2bf(v1) << 16);
            pk.y = (u32)f2bf(v2) | ((u32)f2bf(v3) << 16);
            *(uint2*)&outp[(size_t)tok * H + h0] = pk;
        }
        // reduce over nn (16 tokens per tile x 2 tiles = all 32 tokens of the block)
#pragma unroll
        for (int r = 0; r < 4; ++r) {
            fs[r] += __shfl_xor(fs[r], 1);
            fs[r] += __shfl_xor(fs[r], 2);
            fs[r] += __shfl_xor(fs[r], 4);
            fs[r] += __shfl_xor(fs[r], 8);
        }
        if (nn == 0) {
#pragma unroll
            for (int r = 0; r < 4; ++r)
                psum[(size_t)blk * H + h0 + r] = fs[r];
        }
    }
}

// ---------------- Kernel 2: scores -> masked softmax -> weighted sum ----------------------
// grid.x = 640; block = 512. Rows staged into LDS during phase 1 (free — phase 1 loads
// them anyway); phase 3 reads LDS instead of re-reading 21 MB through L2/L3.
__global__ __launch_bounds__(512) void attn_kernel(
    const u16* __restrict__ ta, const u16* __restrict__ tb,
    const int* __restrict__ mask_a, const int* __restrict__ mask_b,
    const float* __restrict__ psum_a, const float* __restrict__ psum_b,
    float* __restrict__ out)
{
    int n = blockIdx.x;
    int side = 0;
    if (n >= NREV) { side = 1; n -= NREV; }

    const u16* t = side ? tb : ta;
    const int* mask = side ? mask_b : mask_a;
    const float* psum_o = side ? psum_a : psum_b;   // partial sums of the OTHER side
    float* out_vec = out + (side ? NREV * H : 0);
    float* out_w = out + 2 * NREV * H + (side ? NREV * H : 0);

    int sample = n / 10;
    int tid = threadIdx.x;

    __shared__ __align__(16) u16 T_s[128 * 128];    // 32 KB row cache (bf16 bits)
    __shared__ float fbuf[32 * 128];                // 16 KB: score_part then part_out
    __shared__ float mean_s[128];
    __shared__ float w_s[128];
    __shared__ float red[8];

    if (tid < 128) {
        const float* pb = psum_o + (size_t)sample * FC_BLKS_PER_SAMPLE * H + tid;
        float s0 = 0.f, s1 = 0.f, s2 = 0.f, s3 = 0.f;
#pragma unroll
        for (int i = 0; i < FC_BLKS_PER_SAMPLE; i += 4) {
            s0 += pb[(size_t)(i + 0) * H];
            s1 += pb[(size_t)(i + 1) * H];
            s2 += pb[(size_t)(i + 2) * H];
            s3 += pb[(size_t)(i + 3) * H];
        }
        mean_s[tid] = (s0 + s1 + s2 + s3) * (1.0f / (float)TOK_PER_SAMPLE);
    }
    __syncthreads();

    const u16* rowbase = t + (size_t)n * 128 * H;

    // Phase 1: streaming score partials + LDS row staging; uint4 = 8 bf16 per load.
#pragma unroll
    for (int i = 0; i < 4; ++i) {
        int q = tid + 512 * i;          // 0..2047
        int r = q >> 4;                 // row
        int c8 = q & 15;                // group of 8 features
        uint4 v = *(const uint4*)&rowbase[r * H + c8 * 8];
        *(uint4*)&T_s[r * H + c8 * 8] = v;
        const float* m = &mean_s[c8 * 8];
        float p = 0.f;
        p += bf2f((u16)(v.x & 0xffff)) * m[0];
        p += bf2f((u16)(v.x >> 16)) * m[1];
        p += bf2f((u16)(v.y & 0xffff)) * m[2];
        p += bf2f((u16)(v.y >> 16)) * m[3];
        p += bf2f((u16)(v.z & 0xffff)) * m[4];
        p += bf2f((u16)(v.z >> 16)) * m[5];
        p += bf2f((u16)(v.w & 0xffff)) * m[6];
        p += bf2f((u16)(v.w >> 16)) * m[7];
        fbuf[r * 17 + c8] = p;          // score_part view
    }
    __syncthreads();

    // Phase 2: row sums -> masked softmax (threads >=128 carry -1e9 / exp->0, harmless)
    float logit = -1e9f;
    if (tid < 128) {
        float s = 0.f;
#pragma unroll
        for (int j = 0; j < 16; ++j) s += fbuf[tid * 17 + j];
        int mv = mask[n * 128 + tid];
        logit = (mv > 0) ? s : -1e9f;
    }

    float mx = logit;
    for (int off = 32; off > 0; off >>= 1) mx = fmaxf(mx, __shfl_xor(mx, off));
    if ((tid & 63) == 0) red[tid >> 6] = mx;
    __syncthreads();
    mx = red[0];
#pragma unroll
    for (int rr = 1; rr < 8; ++rr) mx = fmaxf(mx, red[rr]);
    __syncthreads();

    float e = __expf(logit - mx);
    float ssum = e;
    for (int off = 32; off > 0; off >>= 1) ssum += __shfl_xor(ssum, off);
    if ((tid & 63) == 0) red[tid >> 6] = ssum;
    __syncthreads();
    ssum = 0.f;
#pragma unroll
    for (int rr = 0; rr < 8; ++rr) ssum += red[rr];

    float w = e / ssum;
    if (tid < 128) {
        w_s[tid] = w;
        out_w[n * 128 + tid] = w;
    }
    __syncthreads();    // also separates score_part reads from part_out writes

    // Phase 3: out[d] = sum_l w_l * row_l[d] from LDS rows; 32 l-partitions.
    int c8 = tid & 15;   // 8 features
    int lp = tid >> 4;   // 32 l-partitions
    float o[8] = {0.f, 0.f, 0.f, 0.f, 0.f, 0.f, 0.f, 0.f};
#pragma unroll
    for (int k = 0; k < 4; ++k) {
        int l = k * 32 + lp;
        float wl = w_s[l];
        uint4 v = *(const uint4*)&T_s[l * H + c8 * 8];
        o[0] = fmaf(wl, bf2f((u16)(v.x & 0xffff)), o[0]);
        o[1] = fmaf(wl, bf2f((u16)(v.x >> 16)), o[1]);
        o[2] = fmaf(wl, bf2f((u16)(v.y & 0xffff)), o[2]);
        o[3] = fmaf(wl, bf2f((u16)(v.y >> 16)), o[3]);
        o[4] = fmaf(wl, bf2f((u16)(v.z & 0xffff)), o[4]);
        o[5] = fmaf(wl, bf2f((u16)(v.z >> 16)), o[5]);
        o[6] = fmaf(wl, bf2f((u16)(v.w & 0xffff)), o[6]);
        o[7] = fmaf(wl, bf2f((u16)(v.w >> 16)), o[7]);
    }
    *(float4*)&fbuf[lp * 128 + c8 * 8] = make_float4(o[0], o[1], o[2], o[3]);       // part_out view
    *(float4*)&fbuf[lp * 128 + c8 * 8 + 4] = make_float4(o[4], o[5], o[6], o[7]);
    __syncthreads();
    if (tid < 128) {
        float s = 0.f;
#pragma unroll
        for (int p = 0; p < 32; ++p) s += fbuf[p * 128 + tid];
        out_vec[n * 128 + tid] = s;
    }
}

// ---------------- Launch ----------------
extern "C" void kernel_launch(void* const* d_in, const int* in_sizes, int n_in,
                              void* d_out, int out_size, void* d_ws, size_t ws_size,
                              hipStream_t stream)
{
    const float* seq_a = (const float*)d_in[0];
    const float* seq_b = (const float*)d_in[1];
    const int* mask_a = (const int*)d_in[2];
    const int* mask_b = (const int*)d_in[3];
    const float* W = (const float*)d_in[4];
    const float* bias = (const float*)d_in[5];
    float* out = (float*)d_out;

    u16* ta = (u16*)d_ws;                             // 40960*128 bf16
    u16* tb = ta + (size_t)NTOK * H;                  // 40960*128 bf16
    float* psum_a = (float*)(tb + (size_t)NTOK * H);  // 1280*128 f32
    float* psum_b = psum_a + FC_BLKS_PER_SIDE * H;    // 1280*128 f32
    u16* Wfrag = (u16*)(psum_b + FC_BLKS_PER_SIDE * H); // 40960 f16

    wsplit_kernel<<<(WFRAG_ELEMS + 255) / 256, 256, 0, stream>>>(W, Wfrag);
    fc_mfma_kernel<<<2 * FC_BLKS_PER_SIDE, 256, 0, stream>>>(seq_a, seq_b, Wfrag, bias, ta, tb, psum_a, psum_b);
    attn_kernel<<<640, 512, 0, stream>>>(ta, tb, mask_a, mask_b, psum_a, psum_b, out);
}

// Round 10
// 146.798 us; speedup vs baseline: 1.1924x; 1.1924x over previous
//
#include <hip/hip_runtime.h>
#include <hip/hip_bf16.h>

// Shapes: bz=32, rv_num=10, rv_len=128, in_feat=300, out_feat=128
// N = 320 reviews/side, tokens/side = 40960, M = 1280 tokens/sample.

#define K_FEAT 300
#define H 128
#define NTOK 40960
#define NREV 320
#define TOK_PER_SAMPLE 1280
#define TM 32                       // tokens per fc block
#define FC_BLKS_PER_SIDE 1280       // 40960/32
#define FC_BLKS_PER_SAMPLE 40       // 1280/32
#define NCHUNK 10
#define WFRAG_ELEMS (NCHUNK * 4 * 2 * 64 * 8)   // 40960 f16 = 80 KB

typedef _Float16 f16;
typedef __attribute__((ext_vector_type(8))) _Float16 f16x8;
typedef __attribute__((ext_vector_type(4))) float f32x4;
typedef unsigned short u16;
typedef unsigned int u32;

static __device__ __forceinline__ u16 f2bf(float x) {
    u32 u = __float_as_uint(x);
    return (u16)((u + 0x7fffu + ((u >> 16) & 1u)) >> 16);
}
static __device__ __forceinline__ float bf2f(u16 s) {
    return __uint_as_float(((u32)s) << 16);
}
static __device__ __forceinline__ u16 f2h_bits(float x) {
    f16 h = (f16)x;
    return *(u16*)&h;
}
static __device__ __forceinline__ u32 pk2h(float a, float b) {
    return (u32)f2h_bits(a) | ((u32)f2h_bits(b) << 16);
}

// ---------------- Kernel 0: pack W into f16 MFMA fragments --------------------------------
// Wfrag[c][p][t2][lane][8]; h = (2*p + t2)*16 + (lane&15).
// Chunks 0..8: k = c*32 + (lane>>4)*8 + j (all < 300).
// Chunk 9: k = 268 + (lane>>4)*8 + j (268..299, in-bounds); entries with k < 288 are
// ZEROED — the fc A-load for chunk 9 reads k=268..299 (overlapping chunk 8, which avoids
// any OOB masking on the A side), and the zeros prevent double-counting the overlap.
__global__ void wsplit_kernel(const float* __restrict__ W, u16* __restrict__ Wfrag)
{
    int i = blockIdx.x * 256 + threadIdx.x;
    if (i >= WFRAG_ELEMS) return;
    int j    = i & 7;
    int lane = (i >> 3) & 63;
    int t2   = (i >> 9) & 1;
    int p    = (i >> 10) & 3;
    int c    = i >> 12;
    int nn = lane & 15, quad = lane >> 4;
    int h = (2 * p + t2) * 16 + nn;
    float w;
    if (c < 9) {
        int k = c * 32 + quad * 8 + j;          // <= 287, always valid
        w = W[(size_t)k * H + h];
    } else {
        int k = 268 + quad * 8 + j;             // 268..299, always valid index
        w = (k >= 288) ? W[(size_t)k * H + h] : 0.f;
    }
    Wfrag[i] = f2h_bits(w);
}

// ---------------- Kernel 1: FC + ReLU, f16 MFMA, ASYNC global->LDS staging ---------------
// grid.x = 2560; block = 256 (4 waves). Tile 32 tok x 128 feat.
// Staging: per chunk, each wave issues ONE __builtin_amdgcn_global_load_lds (16B/lane,
// lane-linear LDS dest) — fire-and-forget, NO vmcnt wait, NO VGPR transit, NO cvt on the
// staging path. All 10 chunks' loads from all waves are in flight simultaneously; the only
// wait is the single __syncthreads() drain. f32 lives in LDS (40 KB, token-major 128B rows,
// XOR-swizzled 16B slots); cvt f32->f16 happens in the sweep, overlapped with MFMA.
// Swizzle (both-sides-or-neither): LDS physical slot (tok, s) holds logical slot
// s^(tok&7); staging pre-permutes the per-lane GLOBAL source address (coalescing intact:
// each 8-lane group still covers one 128B row segment, permuted); sweep reads with the
// same XOR -> bank conflicts reduced to 2-way (free).
__global__ __launch_bounds__(256, 4) void fc_mfma_kernel(
    const float* __restrict__ seq_a, const float* __restrict__ seq_b,
    const u16* __restrict__ Wfrag, const float* __restrict__ bias,
    u16* __restrict__ ta, u16* __restrict__ tb,
    float* __restrict__ psum_a, float* __restrict__ psum_b)
{
    __shared__ __align__(16) float A_s[NCHUNK * 1024];   // 40960 B

    int blk = blockIdx.x;
    const float* seq; u16* outp; float* psum;
    if (blk < FC_BLKS_PER_SIDE) { seq = seq_a; outp = ta; psum = psum_a; }
    else { seq = seq_b; outp = tb; psum = psum_b; blk -= FC_BLKS_PER_SIDE; }

    const int tid = threadIdx.x;
    const int tok0 = blk * TM;
    const int wave = tid >> 6;
    const int lane = tid & 63;
    const int nn = lane & 15;
    const int quad = lane >> 4;

    // ---- Phase 1: async staging. Physical slot for this lane: (tok_s, s_raw); it must
    // hold logical 16B slot s_log = s_raw ^ (tok_s & 7) of the row.
    {
        const int tok_s = tid >> 3;             // 0..31
        const int s_raw = tid & 7;
        const int s_log = s_raw ^ (tok_s & 7);
        const float* gbase = seq + (size_t)(tok0 + tok_s) * K_FEAT + s_log * 4;
#pragma unroll
        for (int c = 0; c < NCHUNK; ++c) {
            const float* gp = gbase + ((c < 9) ? c * 32 : 268);
            float* lp = &A_s[c * 1024 + wave * 256];    // wave-uniform; dest += lane*16B
            __builtin_amdgcn_global_load_lds(
                (const __attribute__((address_space(1))) u32*)gp,
                (__attribute__((address_space(3))) u32*)lp,
                16, 0, 0);
        }
    }
    __syncthreads();    // the ONLY barrier: drains all 10 in-flight loads at once

    f32x4 acc[2][2];                    // [tok-tile m][h-tile t2]
#pragma unroll
    for (int m = 0; m < 2; ++m) {
        acc[m][0] = (f32x4){0.f, 0.f, 0.f, 0.f};
        acc[m][1] = (f32x4){0.f, 0.f, 0.f, 0.f};
    }

    // Per-lane W base: wave's h-pair, this lane's fragment row. L2-hot.
    const u16* wbase = Wfrag + (size_t)wave * 1024 + (size_t)lane * 8;
    const int nn7 = nn & 7;

    // ---- Phase 2: barrier-free MFMA sweep. Per chunk: 2 W loads, 4 swizzled ds_reads,
    // 8 pk2h cvt (overlaps MFMA), 4 MFMAs. Fully unrolled; waves free-run.
#pragma unroll
    for (int c = 0; c < NCHUNK; ++c) {
        f16x8 wh0 = *(const f16x8*)&wbase[(size_t)c * 4096];
        f16x8 wh1 = *(const f16x8*)&wbase[(size_t)c * 4096 + 512];
#pragma unroll
        for (int m = 0; m < 2; ++m) {
            const int rowf = c * 1024 + m * 512 + nn * 32;      // row base (floats)
            float4 f0 = *(const float4*)&A_s[rowf + (((2 * quad)     ^ nn7) << 2)];
            float4 f1 = *(const float4*)&A_s[rowf + (((2 * quad + 1) ^ nn7) << 2)];
            uint4 pkt;
            pkt.x = pk2h(f0.x, f0.y);
            pkt.y = pk2h(f0.z, f0.w);
            pkt.z = pk2h(f1.x, f1.y);
            pkt.w = pk2h(f1.z, f1.w);
            f16x8 a = *reinterpret_cast<f16x8*>(&pkt);
            // swapped: D[h][tok]
            acc[m][0] = __builtin_amdgcn_mfma_f32_16x16x32_f16(wh0, a, acc[m][0], 0, 0, 0);
            acc[m][1] = __builtin_amdgcn_mfma_f32_16x16x32_f16(wh1, a, acc[m][1], 0, 0, 0);
        }
    }

    // Epilogue: lane holds h = (2*wave+ht)*16 + quad*4 + r, tok = tok0 + m*16 + nn.
#pragma unroll
    for (int ht = 0; ht < 2; ++ht) {
        const int h0 = (2 * wave + ht) * 16 + quad * 4;
        const float4 bb = *(const float4*)&bias[h0];    // L1-hot global
        float fs[4] = {0.f, 0.f, 0.f, 0.f};
#pragma unroll
        for (int m = 0; m < 2; ++m) {
            int tok = tok0 + m * 16 + nn;
            float v0 = fmaxf(acc[m][ht][0] + bb.x, 0.f);
            float v1 = fmaxf(acc[m][ht][1] + bb.y, 0.f);
            float v2 = fmaxf(acc[m][ht][2] + bb.z, 0.f);
            float v3 = fmaxf(acc[m][ht][3] + bb.w, 0.f);
            fs[0] += v0; fs[1] += v1; fs[2] += v2; fs[3] += v3;
            uint2 pk;
            pk.x = (u32)f2bf(v0) | ((u32)f2bf(v1) << 16);
            pk.y = (u32)f2bf(v2) | ((u32)f2bf(v3) << 16);
            *(uint2*)&outp[(size_t)tok * H + h0] = pk;
        }
        // reduce over nn (16 tokens per tile x 2 tiles = all 32 tokens of the block)
#pragma unroll
        for (int r = 0; r < 4; ++r) {
            fs[r] += __shfl_xor(fs[r], 1);
            fs[r] += __shfl_xor(fs[r], 2);
            fs[r] += __shfl_xor(fs[r], 4);
            fs[r] += __shfl_xor(fs[r], 8);
        }
        if (nn == 0) {
#pragma unroll
            for (int r = 0; r < 4; ++r)
                psum[(size_t)blk * H + h0 + r] = fs[r];
        }
    }
}

// ---------------- Kernel 2: scores -> masked softmax -> weighted sum ----------------------
// grid.x = 640; block = 512. Rows staged into LDS during phase 1 (free — phase 1 loads
// them anyway); phase 3 reads LDS instead of re-reading 21 MB through L2/L3.
__global__ __launch_bounds__(512) void attn_kernel(
    const u16* __restrict__ ta, const u16* __restrict__ tb,
    const int* __restrict__ mask_a, const int* __restrict__ mask_b,
    const float* __restrict__ psum_a, const float* __restrict__ psum_b,
    float* __restrict__ out)
{
    int n = blockIdx.x;
    int side = 0;
    if (n >= NREV) { side = 1; n -= NREV; }

    const u16* t = side ? tb : ta;
    const int* mask = side ? mask_b : mask_a;
    const float* psum_o = side ? psum_a : psum_b;   // partial sums of the OTHER side
    float* out_vec = out + (side ? NREV * H : 0);
    float* out_w = out + 2 * NREV * H + (side ? NREV * H : 0);

    int sample = n / 10;
    int tid = threadIdx.x;

    __shared__ __align__(16) u16 T_s[128 * 128];    // 32 KB row cache (bf16 bits)
    __shared__ float fbuf[32 * 128];                // 16 KB: score_part then part_out
    __shared__ float mean_s[128];
    __shared__ float w_s[128];
    __shared__ float red[8];

    if (tid < 128) {
        const float* pb = psum_o + (size_t)sample * FC_BLKS_PER_SAMPLE * H + tid;
        float s0 = 0.f, s1 = 0.f, s2 = 0.f, s3 = 0.f;
#pragma unroll
        for (int i = 0; i < FC_BLKS_PER_SAMPLE; i += 4) {
            s0 += pb[(size_t)(i + 0) * H];
            s1 += pb[(size_t)(i + 1) * H];
            s2 += pb[(size_t)(i + 2) * H];
            s3 += pb[(size_t)(i + 3) * H];
        }
        mean_s[tid] = (s0 + s1 + s2 + s3) * (1.0f / (float)TOK_PER_SAMPLE);
    }
    __syncthreads();

    const u16* rowbase = t + (size_t)n * 128 * H;

    // Phase 1: streaming score partials + LDS row staging; uint4 = 8 bf16 per load.
#pragma unroll
    for (int i = 0; i < 4; ++i) {
        int q = tid + 512 * i;          // 0..2047
        int r = q >> 4;                 // row
        int c8 = q & 15;                // group of 8 features
        uint4 v = *(const uint4*)&rowbase[r * H + c8 * 8];
        *(uint4*)&T_s[r * H + c8 * 8] = v;
        const float* m = &mean_s[c8 * 8];
        float p = 0.f;
        p += bf2f((u16)(v.x & 0xffff)) * m[0];
        p += bf2f((u16)(v.x >> 16)) * m[1];
        p += bf2f((u16)(v.y & 0xffff)) * m[2];
        p += bf2f((u16)(v.y >> 16)) * m[3];
        p += bf2f((u16)(v.z & 0xffff)) * m[4];
        p += bf2f((u16)(v.z >> 16)) * m[5];
        p += bf2f((u16)(v.w & 0xffff)) * m[6];
        p += bf2f((u16)(v.w >> 16)) * m[7];
        fbuf[r * 17 + c8] = p;          // score_part view
    }
    __syncthreads();

    // Phase 2: row sums -> masked softmax (threads >=128 carry -1e9 / exp->0, harmless)
    float logit = -1e9f;
    if (tid < 128) {
        float s = 0.f;
#pragma unroll
        for (int j = 0; j < 16; ++j) s += fbuf[tid * 17 + j];
        int mv = mask[n * 128 + tid];
        logit = (mv > 0) ? s : -1e9f;
    }

    float mx = logit;
    for (int off = 32; off > 0; off >>= 1) mx = fmaxf(mx, __shfl_xor(mx, off));
    if ((tid & 63) == 0) red[tid >> 6] = mx;
    __syncthreads();
    mx = red[0];
#pragma unroll
    for (int rr = 1; rr < 8; ++rr) mx = fmaxf(mx, red[rr]);
    __syncthreads();

    float e = __expf(logit - mx);
    float ssum = e;
    for (int off = 32; off > 0; off >>= 1) ssum += __shfl_xor(ssum, off);
    if ((tid & 63) == 0) red[tid >> 6] = ssum;
    __syncthreads();
    ssum = 0.f;
#pragma unroll
    for (int rr = 0; rr < 8; ++rr) ssum += red[rr];

    float w = e / ssum;
    if (tid < 128) {
        w_s[tid] = w;
        out_w[n * 128 + tid] = w;
    }
    __syncthreads();    // also separates score_part reads from part_out writes

    // Phase 3: out[d] = sum_l w_l * row_l[d] from LDS rows; 32 l-partitions.
    int c8 = tid & 15;   // 8 features
    int lp = tid >> 4;   // 32 l-partitions
    float o[8] = {0.f, 0.f, 0.f, 0.f, 0.f, 0.f, 0.f, 0.f};
#pragma unroll
    for (int k = 0; k < 4; ++k) {
        int l = k * 32 + lp;
        float wl = w_s[l];
        uint4 v = *(const uint4*)&T_s[l * H + c8 * 8];
        o[0] = fmaf(wl, bf2f((u16)(v.x & 0xffff)), o[0]);
        o[1] = fmaf(wl, bf2f((u16)(v.x >> 16)), o[1]);
        o[2] = fmaf(wl, bf2f((u16)(v.y & 0xffff)), o[2]);
        o[3] = fmaf(wl, bf2f((u16)(v.y >> 16)), o[3]);
        o[4] = fmaf(wl, bf2f((u16)(v.z & 0xffff)), o[4]);
        o[5] = fmaf(wl, bf2f((u16)(v.z >> 16)), o[5]);
        o[6] = fmaf(wl, bf2f((u16)(v.w & 0xffff)), o[6]);
        o[7] = fmaf(wl, bf2f((u16)(v.w >> 16)), o[7]);
    }
    *(float4*)&fbuf[lp * 128 + c8 * 8] = make_float4(o[0], o[1], o[2], o[3]);       // part_out view
    *(float4*)&fbuf[lp * 128 + c8 * 8 + 4] = make_float4(o[4], o[5], o[6], o[7]);
    __syncthreads();
    if (tid < 128) {
        float s = 0.f;
#pragma unroll
        for (int p = 0; p < 32; ++p) s += fbuf[p * 128 + tid];
        out_vec[n * 128 + tid] = s;
    }
}

// ---------------- Launch ----------------
extern "C" void kernel_launch(void* const* d_in, const int* in_sizes, int n_in,
                              void* d_out, int out_size, void* d_ws, size_t ws_size,
                              hipStream_t stream)
{
    const float* seq_a = (const float*)d_in[0];
    const float* seq_b = (const float*)d_in[1];
    const int* mask_a = (const int*)d_in[2];
    const int* mask_b = (const int*)d_in[3];
    const float* W = (const float*)d_in[4];
    const float* bias = (const float*)d_in[5];
    float* out = (float*)d_out;

    u16* ta = (u16*)d_ws;                             // 40960*128 bf16
    u16* tb = ta + (size_t)NTOK * H;                  // 40960*128 bf16
    float* psum_a = (float*)(tb + (size_t)NTOK * H);  // 1280*128 f32
    float* psum_b = psum_a + FC_BLKS_PER_SIDE * H;    // 1280*128 f32
    u16* Wfrag = (u16*)(psum_b + FC_BLKS_PER_SIDE * H); // 40960 f16

    wsplit_kernel<<<(WFRAG_ELEMS + 255) / 256, 256, 0, stream>>>(W, Wfrag);
    fc_mfma_kernel<<<2 * FC_BLKS_PER_SIDE, 256, 0, stream>>>(seq_a, seq_b, Wfrag, bias, ta, tb, psum_a, psum_b);
    attn_kernel<<<640, 512, 0, stream>>>(ta, tb, mask_a, mask_b, psum_a, psum_b, out);
}

// Round 11
// 145.018 us; speedup vs baseline: 1.2071x; 1.0123x over previous
//
#include <hip/hip_runtime.h>
#include <hip/hip_bf16.h>

// Shapes: bz=32, rv_num=10, rv_len=128, in_feat=300, out_feat=128
// N = 320 reviews/side, tokens/side = 40960, M = 1280 tokens/sample.

#define K_FEAT 300
#define H 128
#define NTOK 40960
#define NREV 320
#define TOK_PER_SAMPLE 1280
#define TM 32                       // tokens per fc block
#define FC_BLKS_PER_SIDE 1280       // 40960/32
#define FC_BLKS_PER_SAMPLE 40       // 1280/32
#define NCHUNK 10
#define WFRAG_ELEMS (NCHUNK * 4 * 2 * 64 * 8)   // 40960 f16 = 80 KB

typedef _Float16 f16;
typedef __attribute__((ext_vector_type(8))) _Float16 f16x8;
typedef __attribute__((ext_vector_type(4))) float f32x4;
typedef unsigned short u16;
typedef unsigned int u32;

static __device__ __forceinline__ u16 f2bf(float x) {
    u32 u = __float_as_uint(x);
    return (u16)((u + 0x7fffu + ((u >> 16) & 1u)) >> 16);
}
static __device__ __forceinline__ float bf2f(u16 s) {
    return __uint_as_float(((u32)s) << 16);
}
static __device__ __forceinline__ u16 f2h_bits(float x) {
    f16 h = (f16)x;
    return *(u16*)&h;
}
static __device__ __forceinline__ u32 pk2h(float a, float b) {
    return (u32)f2h_bits(a) | ((u32)f2h_bits(b) << 16);
}

// ---------------- Kernel 0: pack W into f16 MFMA fragments --------------------------------
// Wfrag[c][p][t2][lane][8]; h = (2*p + t2)*16 + (lane&15).
// Chunks 0..8: k = c*32 + (lane>>4)*8 + j (all < 300).
// Chunk 9: k = 268 + (lane>>4)*8 + j (268..299, in-bounds); entries with k < 288 are
// ZEROED — the fc A-load for chunk 9 reads k=268..299 (overlapping chunk 8, which avoids
// any OOB masking on the A side), and the zeros prevent double-counting the overlap.
__global__ void wsplit_kernel(const float* __restrict__ W, u16* __restrict__ Wfrag)
{
    int i = blockIdx.x * 256 + threadIdx.x;
    if (i >= WFRAG_ELEMS) return;
    int j    = i & 7;
    int lane = (i >> 3) & 63;
    int t2   = (i >> 9) & 1;
    int p    = (i >> 10) & 3;
    int c    = i >> 12;
    int nn = lane & 15, quad = lane >> 4;
    int h = (2 * p + t2) * 16 + nn;
    float w;
    if (c < 9) {
        int k = c * 32 + quad * 8 + j;          // <= 287, always valid
        w = W[(size_t)k * H + h];
    } else {
        int k = 268 + quad * 8 + j;             // 268..299, always valid index
        w = (k >= 288) ? W[(size_t)k * H + h] : 0.f;
    }
    Wfrag[i] = f2h_bits(w);
}

// ---------------- Kernel 1: FC + ReLU, f16 MFMA, W-IN-REGISTERS sweep --------------------
// grid.x = 2560; block = 256 (4 waves). Tile 32 tok x 128 feat.
// R10 diagnosis: fc time tracks the W global loads inside the MFMA loop (R3: 4/chunk=83us,
// R1..R10: 2/chunk=42us) — each wave serially eats ~20 L2 latencies (VGPR=52: compiler
// never hoisted them). Fix: hoist the wave's ENTIRE W working set (10 chunks x 2 frags x
// 16B/lane = 80 VGPRs) into registers BEFORE the barrier; its latency hides under the
// async-staging drain. The sweep then has ZERO global loads: pure ds_read->cvt->MFMA with
// fully independent chunks. __launch_bounds__(256,3) (~170 VGPR cap) guarantees no spill.
// Staging (unchanged from R10): per chunk ONE global_load_lds per wave (16B/lane,
// lane-linear dest), f32 in LDS, XOR-swizzled 16B slots, both-sides-or-neither.
__global__ __launch_bounds__(256, 3) void fc_mfma_kernel(
    const float* __restrict__ seq_a, const float* __restrict__ seq_b,
    const u16* __restrict__ Wfrag, const float* __restrict__ bias,
    u16* __restrict__ ta, u16* __restrict__ tb,
    float* __restrict__ psum_a, float* __restrict__ psum_b)
{
    __shared__ __align__(16) float A_s[NCHUNK * 1024];   // 40960 B

    int blk = blockIdx.x;
    const float* seq; u16* outp; float* psum;
    if (blk < FC_BLKS_PER_SIDE) { seq = seq_a; outp = ta; psum = psum_a; }
    else { seq = seq_b; outp = tb; psum = psum_b; blk -= FC_BLKS_PER_SIDE; }

    const int tid = threadIdx.x;
    const int tok0 = blk * TM;
    const int wave = tid >> 6;
    const int lane = tid & 63;
    const int nn = lane & 15;
    const int quad = lane >> 4;

    // ---- Phase 1a: async A staging (fire-and-forget, no vmcnt wait, no VGPR transit).
    {
        const int tok_s = tid >> 3;             // 0..31
        const int s_raw = tid & 7;
        const int s_log = s_raw ^ (tok_s & 7);
        const float* gbase = seq + (size_t)(tok0 + tok_s) * K_FEAT + s_log * 4;
#pragma unroll
        for (int c = 0; c < NCHUNK; ++c) {
            const float* gp = gbase + ((c < 9) ? c * 32 : 268);
            float* lp = &A_s[c * 1024 + wave * 256];    // wave-uniform; dest += lane*16B
            __builtin_amdgcn_global_load_lds(
                (const __attribute__((address_space(1))) u32*)gp,
                (__attribute__((address_space(3))) u32*)lp,
                16, 0, 0);
        }
    }

    // ---- Phase 1b: hoist ALL W fragments for this wave into registers (80 VGPRs).
    // Latency overlaps the staging drain; the barrier's vmcnt(0) covers both.
    const u16* wbase = Wfrag + (size_t)wave * 1024 + (size_t)lane * 8;
    f16x8 wh[NCHUNK][2];
#pragma unroll
    for (int c = 0; c < NCHUNK; ++c) {
        wh[c][0] = *(const f16x8*)&wbase[(size_t)c * 4096];
        wh[c][1] = *(const f16x8*)&wbase[(size_t)c * 4096 + 512];
    }

    __syncthreads();    // the ONLY barrier: drains staging + W loads together

    f32x4 acc[2][2];                    // [tok-tile m][h-tile t2]
#pragma unroll
    for (int m = 0; m < 2; ++m) {
        acc[m][0] = (f32x4){0.f, 0.f, 0.f, 0.f};
        acc[m][1] = (f32x4){0.f, 0.f, 0.f, 0.f};
    }

    const int nn7 = nn & 7;

    // ---- Phase 2: ZERO-global-load MFMA sweep. Per chunk: 4 swizzled ds_read_b128,
    // 8 pk2h cvt (overlaps MFMA), 4 MFMAs. Chunks fully independent; waves free-run.
#pragma unroll
    for (int c = 0; c < NCHUNK; ++c) {
#pragma unroll
        for (int m = 0; m < 2; ++m) {
            const int rowf = c * 1024 + m * 512 + nn * 32;      // row base (floats)
            float4 f0 = *(const float4*)&A_s[rowf + (((2 * quad)     ^ nn7) << 2)];
            float4 f1 = *(const float4*)&A_s[rowf + (((2 * quad + 1) ^ nn7) << 2)];
            uint4 pkt;
            pkt.x = pk2h(f0.x, f0.y);
            pkt.y = pk2h(f0.z, f0.w);
            pkt.z = pk2h(f1.x, f1.y);
            pkt.w = pk2h(f1.z, f1.w);
            f16x8 a = *reinterpret_cast<f16x8*>(&pkt);
            // swapped: D[h][tok]
            acc[m][0] = __builtin_amdgcn_mfma_f32_16x16x32_f16(wh[c][0], a, acc[m][0], 0, 0, 0);
            acc[m][1] = __builtin_amdgcn_mfma_f32_16x16x32_f16(wh[c][1], a, acc[m][1], 0, 0, 0);
        }
    }

    // Epilogue: lane holds h = (2*wave+ht)*16 + quad*4 + r, tok = tok0 + m*16 + nn.
#pragma unroll
    for (int ht = 0; ht < 2; ++ht) {
        const int h0 = (2 * wave + ht) * 16 + quad * 4;
        const float4 bb = *(const float4*)&bias[h0];    // L1-hot global
        float fs[4] = {0.f, 0.f, 0.f, 0.f};
#pragma unroll
        for (int m = 0; m < 2; ++m) {
            int tok = tok0 + m * 16 + nn;
            float v0 = fmaxf(acc[m][ht][0] + bb.x, 0.f);
            float v1 = fmaxf(acc[m][ht][1] + bb.y, 0.f);
            float v2 = fmaxf(acc[m][ht][2] + bb.z, 0.f);
            float v3 = fmaxf(acc[m][ht][3] + bb.w, 0.f);
            fs[0] += v0; fs[1] += v1; fs[2] += v2; fs[3] += v3;
            uint2 pk;
            pk.x = (u32)f2bf(v0) | ((u32)f2bf(v1) << 16);
            pk.y = (u32)f2bf(v2) | ((u32)f2bf(v3) << 16);
            *(uint2*)&outp[(size_t)tok * H + h0] = pk;
        }
        // reduce over nn (16 tokens per tile x 2 tiles = all 32 tokens of the block)
#pragma unroll
        for (int r = 0; r < 4; ++r) {
            fs[r] += __shfl_xor(fs[r], 1);
            fs[r] += __shfl_xor(fs[r], 2);
            fs[r] += __shfl_xor(fs[r], 4);
            fs[r] += __shfl_xor(fs[r], 8);
        }
        if (nn == 0) {
#pragma unroll
            for (int r = 0; r < 4; ++r)
                psum[(size_t)blk * H + h0 + r] = fs[r];
        }
    }
}

// ---------------- Kernel 2: scores -> masked softmax -> weighted sum ----------------------
// grid.x = 640; block = 512. Rows staged into LDS during phase 1 (free — phase 1 loads
// them anyway); phase 3 reads LDS instead of re-reading 21 MB through L2/L3.
__global__ __launch_bounds__(512) void attn_kernel(
    const u16* __restrict__ ta, const u16* __restrict__ tb,
    const int* __restrict__ mask_a, const int* __restrict__ mask_b,
    const float* __restrict__ psum_a, const float* __restrict__ psum_b,
    float* __restrict__ out)
{
    int n = blockIdx.x;
    int side = 0;
    if (n >= NREV) { side = 1; n -= NREV; }

    const u16* t = side ? tb : ta;
    const int* mask = side ? mask_b : mask_a;
    const float* psum_o = side ? psum_a : psum_b;   // partial sums of the OTHER side
    float* out_vec = out + (side ? NREV * H : 0);
    float* out_w = out + 2 * NREV * H + (side ? NREV * H : 0);

    int sample = n / 10;
    int tid = threadIdx.x;

    __shared__ __align__(16) u16 T_s[128 * 128];    // 32 KB row cache (bf16 bits)
    __shared__ float fbuf[32 * 128];                // 16 KB: score_part then part_out
    __shared__ float mean_s[128];
    __shared__ float w_s[128];
    __shared__ float red[8];

    if (tid < 128) {
        const float* pb = psum_o + (size_t)sample * FC_BLKS_PER_SAMPLE * H + tid;
        float s0 = 0.f, s1 = 0.f, s2 = 0.f, s3 = 0.f;
#pragma unroll
        for (int i = 0; i < FC_BLKS_PER_SAMPLE; i += 4) {
            s0 += pb[(size_t)(i + 0) * H];
            s1 += pb[(size_t)(i + 1) * H];
            s2 += pb[(size_t)(i + 2) * H];
            s3 += pb[(size_t)(i + 3) * H];
        }
        mean_s[tid] = (s0 + s1 + s2 + s3) * (1.0f / (float)TOK_PER_SAMPLE);
    }
    __syncthreads();

    const u16* rowbase = t + (size_t)n * 128 * H;

    // Phase 1: streaming score partials + LDS row staging; uint4 = 8 bf16 per load.
#pragma unroll
    for (int i = 0; i < 4; ++i) {
        int q = tid + 512 * i;          // 0..2047
        int r = q >> 4;                 // row
        int c8 = q & 15;                // group of 8 features
        uint4 v = *(const uint4*)&rowbase[r * H + c8 * 8];
        *(uint4*)&T_s[r * H + c8 * 8] = v;
        const float* m = &mean_s[c8 * 8];
        float p = 0.f;
        p += bf2f((u16)(v.x & 0xffff)) * m[0];
        p += bf2f((u16)(v.x >> 16)) * m[1];
        p += bf2f((u16)(v.y & 0xffff)) * m[2];
        p += bf2f((u16)(v.y >> 16)) * m[3];
        p += bf2f((u16)(v.z & 0xffff)) * m[4];
        p += bf2f((u16)(v.z >> 16)) * m[5];
        p += bf2f((u16)(v.w & 0xffff)) * m[6];
        p += bf2f((u16)(v.w >> 16)) * m[7];
        fbuf[r * 17 + c8] = p;          // score_part view
    }
    __syncthreads();

    // Phase 2: row sums -> masked softmax (threads >=128 carry -1e9 / exp->0, harmless)
    float logit = -1e9f;
    if (tid < 128) {
        float s = 0.f;
#pragma unroll
        for (int j = 0; j < 16; ++j) s += fbuf[tid * 17 + j];
        int mv = mask[n * 128 + tid];
        logit = (mv > 0) ? s : -1e9f;
    }

    float mx = logit;
    for (int off = 32; off > 0; off >>= 1) mx = fmaxf(mx, __shfl_xor(mx, off));
    if ((tid & 63) == 0) red[tid >> 6] = mx;
    __syncthreads();
    mx = red[0];
#pragma unroll
    for (int rr = 1; rr < 8; ++rr) mx = fmaxf(mx, red[rr]);
    __syncthreads();

    float e = __expf(logit - mx);
    float ssum = e;
    for (int off = 32; off > 0; off >>= 1) ssum += __shfl_xor(ssum, off);
    if ((tid & 63) == 0) red[tid >> 6] = ssum;
    __syncthreads();
    ssum = 0.f;
#pragma unroll
    for (int rr = 0; rr < 8; ++rr) ssum += red[rr];

    float w = e / ssum;
    if (tid < 128) {
        w_s[tid] = w;
        out_w[n * 128 + tid] = w;
    }
    __syncthreads();    // also separates score_part reads from part_out writes

    // Phase 3: out[d] = sum_l w_l * row_l[d] from LDS rows; 32 l-partitions.
    int c8 = tid & 15;   // 8 features
    int lp = tid >> 4;   // 32 l-partitions
    float o[8] = {0.f, 0.f, 0.f, 0.f, 0.f, 0.f, 0.f, 0.f};
#pragma unroll
    for (int k = 0; k < 4; ++k) {
        int l = k * 32 + lp;
        float wl = w_s[l];
        uint4 v = *(const uint4*)&T_s[l * H + c8 * 8];
        o[0] = fmaf(wl, bf2f((u16)(v.x & 0xffff)), o[0]);
        o[1] = fmaf(wl, bf2f((u16)(v.x >> 16)), o[1]);
        o[2] = fmaf(wl, bf2f((u16)(v.y & 0xffff)), o[2]);
        o[3] = fmaf(wl, bf2f((u16)(v.y >> 16)), o[3]);
        o[4] = fmaf(wl, bf2f((u16)(v.z & 0xffff)), o[4]);
        o[5] = fmaf(wl, bf2f((u16)(v.z >> 16)), o[5]);
        o[6] = fmaf(wl, bf2f((u16)(v.w & 0xffff)), o[6]);
        o[7] = fmaf(wl, bf2f((u16)(v.w >> 16)), o[7]);
    }
    *(float4*)&fbuf[lp * 128 + c8 * 8] = make_float4(o[0], o[1], o[2], o[3]);       // part_out view
    *(float4*)&fbuf[lp * 128 + c8 * 8 + 4] = make_float4(o[4], o[5], o[6], o[7]);
    __syncthreads();
    if (tid < 128) {
        float s = 0.f;
#pragma unroll
        for (int p = 0; p < 32; ++p) s += fbuf[p * 128 + tid];
        out_vec[n * 128 + tid] = s;
    }
}

// ---------------- Launch ----------------
extern "C" void kernel_launch(void* const* d_in, const int* in_sizes, int n_in,
                              void* d_out, int out_size, void* d_ws, size_t ws_size,
                              hipStream_t stream)
{
    const float* seq_a = (const float*)d_in[0];
    const float* seq_b = (const float*)d_in[1];
    const int* mask_a = (const int*)d_in[2];
    const int* mask_b = (const int*)d_in[3];
    const float* W = (const float*)d_in[4];
    const float* bias = (const float*)d_in[5];
    float* out = (float*)d_out;

    u16* ta = (u16*)d_ws;                             // 40960*128 bf16
    u16* tb = ta + (size_t)NTOK * H;                  // 40960*128 bf16
    float* psum_a = (float*)(tb + (size_t)NTOK * H);  // 1280*128 f32
    float* psum_b = psum_a + FC_BLKS_PER_SIDE * H;    // 1280*128 f32
    u16* Wfrag = (u16*)(psum_b + FC_BLKS_PER_SIDE * H); // 40960 f16

    wsplit_kernel<<<(WFRAG_ELEMS + 255) / 256, 256, 0, stream>>>(W, Wfrag);
    fc_mfma_kernel<<<2 * FC_BLKS_PER_SIDE, 256, 0, stream>>>(seq_a, seq_b, Wfrag, bias, ta, tb, psum_a, psum_b);
    attn_kernel<<<640, 512, 0, stream>>>(ta, tb, mask_a, mask_b, psum_a, psum_b, out);
}